// Round 1
// baseline (160.004 us; speedup 1.0000x reference)
//
#include <hip/hip_runtime.h>

#define N 512
#define PAD 514          // N + 2 (1-pixel zero border on each side)
#define NA 180
#define ISPLIT 8         // i-loop split factor for occupancy
#define ICHUNK (N / ISPLIT)

// Build zero-padded image and zero-padded transposed image in workspace.
__global__ __launch_bounds__(256) void pad_kernel(const float* __restrict__ img,
                                                  float* __restrict__ imgP,
                                                  float* __restrict__ imgTP) {
    int idx = blockIdx.x * 256 + threadIdx.x;
    if (idx >= PAD * PAD) return;
    int y = idx / PAD;
    int x = idx - y * PAD;
    bool interior = (y >= 1) && (y <= N) && (x >= 1) && (x <= N);
    float v  = interior ? img[(y - 1) * N + (x - 1)] : 0.0f;
    float vt = interior ? img[(x - 1) * N + (y - 1)] : 0.0f;
    imgP[idx]  = v;
    imgTP[idx] = vt;
}

// One thread per (detector d, angle a, i-chunk). Lanes map to consecutive d
// for coalesced gathers; for 45<theta<135 we sample the transposed image so
// lane-adjacent addresses stay row-contiguous.
__global__ __launch_bounds__(256) void radon_kernel(const float* __restrict__ imgP,
                                                    const float* __restrict__ imgTP,
                                                    const int* __restrict__ angles,
                                                    float* __restrict__ out) {
    const int d  = blockIdx.x * 256 + threadIdx.x;   // 0..511
    const int a  = blockIdx.y;                        // 0..179
    const int i0 = blockIdx.z * ICHUNK;

    const float c = 255.5f;
    const float t = (float)angles[a] * 0.017453292519943295f;  // deg2rad in f32
    float si, co;
    __sincosf(t, &si, &co);
    // use precise versions to match JAX f32 cos/sin closely
    si = sinf(t);
    co = cosf(t);

    const bool useT = fabsf(si) > fabsf(co);
    const float* __restrict__ src = useT ? imgTP : imgP;

    const float xc = (float)d - c;
    // u = column coord, v = row coord in the chosen source image:
    //   normal:     u = sx = co*xc + si*fi + c,  v = sy = -si*xc + co*fi + c
    //   transposed: u = sy,                      v = sx
    float au, bu, av, bv;
    if (useT) { au = co; bu = fmaf(-si, xc, c); av = si; bv = fmaf(co, xc, c); }
    else      { au = si; bu = fmaf(co, xc, c);  av = co; bv = fmaf(-si, xc, c); }

    float sum = 0.0f;
#pragma unroll 4
    for (int k = 0; k < ICHUNK; ++k) {
        float fi = (float)(i0 + k) - c;
        float u = fmaf(au, fi, bu);
        float v = fmaf(av, fi, bv);
        // sample is nonzero only if all contributing corners can be valid;
        // with the 1-px zero border, corners inside (-1,512) read the pad.
        if (u > -1.0f && u < (float)N && v > -1.0f && v < (float)N) {
            float x0 = floorf(u), y0 = floorf(v);
            float wx = u - x0,  wy = v - y0;
            int ix = (int)x0 + 1;            // padded col in [0, 512]
            int iy = (int)y0 + 1;            // padded row in [0, 512]
            const float* p = src + iy * PAD + ix;
            float v00 = p[0],   v01 = p[1];
            float v10 = p[PAD], v11 = p[PAD + 1];
            float top = fmaf(wx, v01 - v00, v00);
            float bot = fmaf(wx, v11 - v10, v10);
            sum += fmaf(wy, bot - top, top);
        }
    }
    atomicAdd(&out[d * NA + a], sum);
}

extern "C" void kernel_launch(void* const* d_in, const int* in_sizes, int n_in,
                              void* d_out, int out_size, void* d_ws, size_t ws_size,
                              hipStream_t stream) {
    const float* img   = (const float*)d_in[0];
    const int* angles  = (const int*)d_in[1];
    float* out   = (float*)d_out;
    float* imgP  = (float*)d_ws;
    float* imgTP = imgP + PAD * PAD;

    // out is poisoned before every timed launch -> zero it (atomicAdd target)
    hipMemsetAsync(d_out, 0, (size_t)out_size * sizeof(float), stream);

    pad_kernel<<<(PAD * PAD + 255) / 256, 256, 0, stream>>>(img, imgP, imgTP);

    dim3 grid(N / 256, NA, ISPLIT);
    radon_kernel<<<grid, 256, 0, stream>>>(imgP, imgTP, angles, out);
}